// Round 10
// baseline (2043.911 us; speedup 1.0000x reference)
//
#include <hip/hip_runtime.h>

// ---------------------------------------------------------------------------
// BiLSTM + CRF on MI355X — R20: scan-CU exclusivity + setprio.
// R19 ledger: 4x199us fused (scan, 75% of total) + ~270us invariant overhead.
// Scan step 1.55us vs 1.46 standalone (+6% interference: VGPR=48 lets shadow
// wgs co-schedule on scan CUs). Fix:
//  (1) shadow gemm -> true dbuf B with NAMED buffers + fully unrolled ci+=2
//      loop (rule-#20-safe, unlike R18's runtime-indexed disaster). VGPR
//      rises >64 -> 1 wg/CU everywhere -> scan CUs exclusive; shadow gemm
//      also finishes sooner (less L2 interference).
//  (2) s_setprio(1) around scan MFMA cluster (T5; harmless if moot).
// Everything else identical to R19.
// ---------------------------------------------------------------------------

typedef short v8s __attribute__((ext_vector_type(8)));
typedef float v4f __attribute__((ext_vector_type(4)));
typedef int   i4v __attribute__((ext_vector_type(4)));
typedef int   i8v __attribute__((ext_vector_type(8)));
typedef float v2f __attribute__((ext_vector_type(2)));

#define LOG2E  1.4426950408889634f
#define LOG2E2 2.8853900817779268f

__device__ __forceinline__ short f2b(float f){
  unsigned u = __float_as_uint(f);
  u = u + 0x7fffu + ((u >> 16) & 1u);          // RNE
  return (short)(u >> 16);
}
__device__ __forceinline__ float b2f(short s){
  return __uint_as_float(((unsigned)(unsigned short)s) << 16);
}
__device__ __forceinline__ float rcp_(float x){ return __builtin_amdgcn_rcpf(x); }
__device__ __forceinline__ float ex2(float x){ return __builtin_amdgcn_exp2f(x); }
__device__ __forceinline__ float med3(float x, float lo, float hi){
  return __builtin_amdgcn_fmed3f(x, lo, hi);
}
// e2m1 nearest: mags {0,.5,1,1.5,2,3,4,6}, code = sign<<3 | mag-index
__device__ __forceinline__ int fp4q(float v){
  int s = (v < 0.f) ? 8 : 0;
  float av = fabsf(v);
  int m;
  if(av < 0.25f) m=0; else if(av < 0.75f) m=1; else if(av < 1.25f) m=2;
  else if(av < 1.75f) m=3; else if(av < 2.5f) m=4; else if(av < 3.5f) m=5;
  else if(av < 5.f) m=6; else m=7;
  return s | m;
}

// ---------------------------------------------------------------------------
// prep: (unchanged — weights/biases gate-scaled for exp2)
// ---------------------------------------------------------------------------
__global__ void prep_kernel(const float* wihf, const float* whhf,
                            const float* wihb, const float* whhb,
                            const float* bihf, const float* bhhf,
                            const float* bihb, const float* bhhb,
                            short* wswz, unsigned char* whh4, int2* whsc,
                            float* cb, float* em, float* outp)
{
  int gid = blockIdx.x * 256 + threadIdx.x;      // 131072 threads
  if(gid < 65536){
    int mat = gid >> 15;                 // 0 = fwd, 1 = bwd
    int rem = gid & 32767;
    int ct = rem >> 9;
    int kk = (rem >> 6) & 7;
    int lane = rem & 63;
    const float* src = mat ? wihb : wihf;
    int g  = ct*16 + (lane & 15);
    float fac = ((g >> 8) == 2) ? LOG2E2 : LOG2E;
    int k0 = kk*32 + (lane >> 4)*8;
    v8s o;
#pragma unroll
    for(int j=0;j<8;j++) o[j] = f2b(src[g*256 + k0 + j] * fac);
    *(v8s*)(wswz + ((long)mat << 18) + ((long)((ct*8+kk)*64 + lane) << 3)) = o;
  } else if(gid < 73728){
    int j2 = gid - 65536;                // 8192
    int dir = j2 >> 12;
    int rem = j2 & 4095;
    int ct = rem >> 6;
    int lane = rem & 63;
    const float* src = dir ? whhb : whhf;
    int g = ct*16 + (lane & 15);
    float fac = ((g >> 8) == 2) ? LOG2E2 : LOG2E;
    int sc0 = 127, sc1 = 127;
#pragma unroll
    for(int half=0; half<2; half++){
      const float* s = src + g*256 + half*128 + (lane>>4)*32;
      float am = 0.f;
#pragma unroll
      for(int j=0;j<32;j++) am = fmaxf(am, fabsf(s[j]*fac));
      int e = 0;
      if(am > 0.f){
        e = (int)ceilf(log2f(am * (1.f/6.f)));
        e = e < -126 ? -126 : (e > 127 ? 127 : e);
      }
      float inv = exp2f((float)(-e)) * fac;
      i4v ov;
#pragma unroll
      for(int wi=0; wi<4; wi++){
        int word = 0;
#pragma unroll
        for(int bj=0; bj<4; bj++){
          int j0 = (wi*4 + bj)*2;        // low nibble = lower k
          int c0 = fp4q(s[j0]*inv), c1 = fp4q(s[j0+1]*inv);
          word |= (c0 | (c1<<4)) << (8*bj);
        }
        ov[wi] = word;
      }
      *(i4v*)(whh4 + ((long)((dir*64+ct)*2 + half) << 10) + lane*16) = ov;
      if(half == 0) sc0 = e + 127; else sc1 = e + 127;
    }
    whsc[(dir*64+ct)*64 + lane] = make_int2(sc0, sc1);
  } else if(gid >= 106496 && gid < 108544){
    int j3 = gid - 106496;
    int dir = j3 >> 10, gg = j3 & 1023;
    float fac = ((gg >> 8) == 2) ? LOG2E2 : LOG2E;
    cb[j3] = fac * (dir ? (bihb[gg] + bhhb[gg]) : (bihf[gg] + bhhf[gg]));
  }
  for(int i=gid; i<589824; i+=131072) em[i] = 0.f;
  if(gid == 0) *outp = 0.f;
}

// ---------------------------------------------------------------------------
// xg_gemm: standalone (chunk 0 only). Unchanged.
// ---------------------------------------------------------------------------
__global__ __launch_bounds__(256,2) void xg_gemm(const int* X, const float* emb,
     const short* wswz, const float* cb, short* xg, int t_base, int CT)
{
  int dir = blockIdx.x & 1;
  int tl  = blockIdx.x >> 1;
  int rh  = blockIdx.y;
  int tg  = t_base + tl;
  int tt  = dir ? (511 - tg) : tg;
  __shared__ short a_sh[64*264];
  int tid = threadIdx.x;
  {
    int row = tid >> 2, seg = tid & 3;
    int b = rh*64 + row;
    int idx = X[b*512 + tt];
    const float* erow = emb + (long)idx*256 + seg*64;
    short* dst = a_sh + row*264 + seg*64;
#pragma unroll
    for(int c=0;c<8;c++){
      float4 f0 = ((const float4*)erow)[2*c];
      float4 f1 = ((const float4*)erow)[2*c+1];
      v8s p;
      p[0]=f2b(f0.x); p[1]=f2b(f0.y); p[2]=f2b(f0.z); p[3]=f2b(f0.w);
      p[4]=f2b(f1.x); p[5]=f2b(f1.y); p[6]=f2b(f1.z); p[7]=f2b(f1.w);
      *(v8s*)(dst + c*8) = p;
    }
  }
  __syncthreads();
  int w = tid >> 6, lane = tid & 63, lm = lane & 15, lq = lane >> 4;
  v8s A[4][8];
#pragma unroll
  for(int mt=0;mt<4;mt++)
#pragma unroll
    for(int kk=0;kk<8;kk++)
      A[mt][kk] = *(const v8s*)(a_sh + (mt*16+lm)*264 + kk*32 + lq*8);

  const short* wmat = wswz + ((long)dir << 18);
  const float* cbd  = cb + dir*1024;
  short* xgd = xg + ((long)dir*CT + tl)*131072;

  v8s Bb[2][8];
  {
    const short* bp = wmat + (long)(w*16)*4096 + lane*8;
#pragma unroll
    for(int kk=0;kk<8;kk++) Bb[0][kk] = *(const v8s*)(bp + kk*512);
  }
#pragma unroll
  for(int ci=0;ci<16;ci++){
    int cur = ci & 1;
    int ct = w*16 + ci;
    if(ci < 15){
      const short* bp = wmat + (long)(ct+1)*4096 + lane*8;
#pragma unroll
      for(int kk=0;kk<8;kk++) Bb[cur^1][kk] = *(const v8s*)(bp + kk*512);
    }
    float bias = cbd[ct*16 + lm];
    v4f acc[4];
#pragma unroll
    for(int mt=0;mt<4;mt++) acc[mt] = (v4f){bias,bias,bias,bias};
#pragma unroll
    for(int kk=0;kk<8;kk++)
#pragma unroll
      for(int mt=0;mt<4;mt++)
        acc[mt] = __builtin_amdgcn_mfma_f32_16x16x32_bf16(A[mt][kk], Bb[cur][kk], acc[mt], 0,0,0);
#pragma unroll
    for(int mt=0;mt<4;mt++){
      int r = rh*4 + mt;
      long off = (long)r*16384 + (long)(ct & 15)*1024 + (ct >> 4)*256 + lane*4;
      short4 s4;
      s4.x = f2b(acc[mt][0]); s4.y = f2b(acc[mt][1]);
      s4.z = f2b(acc[mt][2]); s4.w = f2b(acc[mt][3]);
      *(short4*)(xgd + off) = s4;
    }
  }
}

// ---------------------------------------------------------------------------
// emiss_partial: standalone (last chunk only). Unchanged.
// ---------------------------------------------------------------------------
__global__ void emiss_partial(const unsigned char* hg8, const float* lin_w,
                              float* em, int t_base, int CT)
{
  int dir = blockIdx.y;
  int wv  = blockIdx.x*4 + (threadIdx.x >> 6);
  int lane = threadIdx.x & 63;
  int tl = wv >> 7, b = wv & 127;
  int s = dir ? (511 - (t_base + tl)) : (t_base + tl);
  int v = *(const int*)(hg8 + ((long)dir*CT + tl)*32768 + b*256 + lane*4);
  v2f lo = __builtin_amdgcn_cvt_pk_f32_fp8(v, 0);
  v2f hi = __builtin_amdgcn_cvt_pk_f32_fp8(v, 1);
  float x0 = lo[0], x1 = lo[1], x2 = hi[0], x3 = hi[1];
  const float* wbase = lin_w + dir*256 + lane*4;
  float part[9];
#pragma unroll
  for(int j=0;j<9;j++){
    float4 wf = *(const float4*)(wbase + j*512);
    part[j] = x0*wf.x + x1*wf.y + x2*wf.z + x3*wf.w;
  }
#pragma unroll
  for(int j=0;j<9;j++){
    float vv = part[j];
#pragma unroll
    for(int off=32; off>0; off>>=1) vv += __shfl_down(vv, off);
    if(lane == 0) em[((long)b*512 + s)*9 + j] += vv;
  }
}

// ---------------------------------------------------------------------------
// fused_step: one launch per chunk k.
//   bx < 16     : scan(chunk k)     — R14 body + setprio around MFMA
//   bx < 16+ng  : gemm(chunk k+1)   — dbuf B, NAMED buffers, full unroll
//   else        : emiss(chunk k-1)
// VGPR > 64 (gemm dbuf) + LB(1024,1) => 1 wg/CU => scan CUs exclusive.
// ---------------------------------------------------------------------------
__global__ __launch_bounds__(1024,1) void fused_step(
     const int* __restrict__ X, const float* __restrict__ emb,
     const short* __restrict__ wswz, const float* __restrict__ cb,
     const short* __restrict__ xg_rd, short* __restrict__ xg_wr,
     const unsigned char* __restrict__ whh4, const int2* __restrict__ whsc,
     unsigned char* __restrict__ hg_wr, const unsigned char* __restrict__ hg_rd,
     float* __restrict__ c_state, unsigned char* __restrict__ h_state,
     const float* __restrict__ lin_w, float* __restrict__ em,
     int first, int CT, int tb_gemm, int tb_emiss, int ng)
{
  __shared__ __align__(16) short a_sh4[4*16*264];   // 33,792 B (gemm); scan uses first 8704
  int bx = blockIdx.x;
  int tid = threadIdx.x;

  if(bx < 16){
    // ================= SCAN branch =================
    unsigned char* hbuf = (unsigned char*)a_sh4;
    int wg = bx;
    int dir = wg >> 3, r = wg & 7;
    int w = tid >> 6, lane = tid & 63, lm = lane & 15, lq = lane >> 4;

    i8v B8[4][2];
#pragma unroll
    for(int grp=0; grp<4; grp++)
#pragma unroll
      for(int half=0; half<2; half++){
        i4v b = *(const i4v*)(whh4 + ((long)((dir*64 + grp*16 + w)*2 + half) << 10) + lane*16);
        i8v t;
#pragma unroll
        for(int j=0;j<4;j++){ t[j] = b[j]; t[4+j] = 0; }
        B8[grp][half] = t;
      }
    int scp[2];
#pragma unroll
    for(int gp=0; gp<2; gp++){
      int2 s0 = whsc[(dir*64 + (2*gp+0)*16 + w)*64 + lane];
      int2 s1 = whsc[(dir*64 + (2*gp+1)*16 + w)*64 + lane];
      scp[gp] = (s0.x & 255) | ((s0.y & 255) << 8) | ((s1.x & 255) << 16) | ((s1.y & 255) << 24);
    }

    float c[4];
    if(first){
      for(int i=tid; i<8704; i+=1024) hbuf[i] = 0;
#pragma unroll
      for(int i=0;i<4;i++) c[i] = 0.f;
    } else {
      *(int*)(hbuf + w*272 + lane*4) = *(const int*)(h_state + wg*4096 + w*256 + lane*4);
#pragma unroll
      for(int i=0;i<4;i++) c[i] = c_state[(wg*1024 + tid)*4 + i];
    }
    __syncthreads();

    const short* __restrict__ xbase =
        xg_rd + ((long)dir*CT)*131072 + (long)r*16384 + w*1024 + lane*4;
    unsigned char* __restrict__ hout =
        hg_wr + (long)dir*CT*32768 + (r*16 + w)*256 + lane*4;

    short4 xa0 = *(const short4*)(xbase);
    short4 xa1 = *(const short4*)(xbase + 256);
    short4 xa2 = *(const short4*)(xbase + 512);
    short4 xa3 = *(const short4*)(xbase + 768);

    int p = 0;
    for(int tl=0; tl<CT; tl++){
      const short* __restrict__ xn = xbase + 131072;
      short4 xn0 = *(const short4*)(xn);
      short4 xn1 = *(const short4*)(xn + 256);
      short4 xn2 = *(const short4*)(xn + 512);
      short4 xn3 = *(const short4*)(xn + 768);

      const unsigned char* hb = hbuf + p*4352;
      union { i8v v8; i4v v4[2]; } a0, a1;
      a0.v4[0] = *(const i4v*)(hb + lm*272 + lq*32);
      a0.v4[1] = *(const i4v*)(hb + lm*272 + lq*32 + 16);
      a1.v4[0] = *(const i4v*)(hb + lm*272 + 128 + lq*32);
      a1.v4[1] = *(const i4v*)(hb + lm*272 + 128 + lq*32 + 16);

      v4f acc[4];
      acc[0] = (v4f){b2f(xa0.x), b2f(xa0.y), b2f(xa0.z), b2f(xa0.w)};
      acc[1] = (v4f){b2f(xa1.x), b2f(xa1.y), b2f(xa1.z), b2f(xa1.w)};
      acc[2] = (v4f){b2f(xa2.x), b2f(xa2.y), b2f(xa2.z), b2f(xa2.w)};
      acc[3] = (v4f){b2f(xa3.x), b2f(xa3.y), b2f(xa3.z), b2f(xa3.w)};

      __builtin_amdgcn_s_setprio(1);
      acc[0] = __builtin_amdgcn_mfma_scale_f32_16x16x128_f8f6f4(a0.v8, B8[0][0], acc[0], 0, 4, 0, 127, 0, scp[0]);
      acc[0] = __builtin_amdgcn_mfma_scale_f32_16x16x128_f8f6f4(a1.v8, B8[0][1], acc[0], 0, 4, 0, 127, 1, scp[0]);
      acc[1] = __builtin_amdgcn_mfma_scale_f32_16x16x128_f8f6f4(a0.v8, B8[1][0], acc[1], 0, 4, 0, 127, 2, scp[0]);
      acc[1] = __builtin_amdgcn_mfma_scale_f32_16x16x128_f8f6f4(a1.v8, B8[1][1], acc[1], 0, 4, 0, 127, 3, scp[0]);
      acc[2] = __builtin_amdgcn_mfma_scale_f32_16x16x128_f8f6f4(a0.v8, B8[2][0], acc[2], 0, 4, 0, 127, 0, scp[1]);
      acc[2] = __builtin_amdgcn_mfma_scale_f32_16x16x128_f8f6f4(a1.v8, B8[2][1], acc[2], 0, 4, 0, 127, 1, scp[1]);
      acc[3] = __builtin_amdgcn_mfma_scale_f32_16x16x128_f8f6f4(a0.v8, B8[3][0], acc[3], 0, 4, 0, 127, 2, scp[1]);
      acc[3] = __builtin_amdgcn_mfma_scale_f32_16x16x128_f8f6f4(a1.v8, B8[3][1], acc[3], 0, 4, 0, 127, 3, scp[1]);
      __builtin_amdgcn_s_setprio(0);

      unsigned char* hnew = hbuf + (p^1)*4352;
      {
        int d = 16*w + lm;
        float hv[4];
#pragma unroll
        for(int rr=0;rr<4;rr++){
          float ig = acc[0][rr];
          float fg = acc[1][rr];
          float gg = med3(acc[2][rr], -40.f, 40.f);
          float og = acc[3][rr];
          float t  = ex2(gg);
          float a  = ex2(-ig);
          float b  = ex2(-fg);
          float u  = ex2(-og);
          float term = (t - 1.f) * rcp_((1.f + a)*(1.f + t));
          float cn = c[rr]*rcp_(1.f + b) + term;
          c[rr] = cn;
          float cc = med3(cn*LOG2E2, -40.f, 40.f);
          float d2 = ex2(cc);
          hv[rr] = (d2 - 1.f)*rcp_((1.f + u)*(1.f + d2));
        }
        int packed = __builtin_amdgcn_cvt_pk_fp8_f32(hv[0], hv[1], 0, 0);
        packed = __builtin_amdgcn_cvt_pk_fp8_f32(hv[2], hv[3], packed, 1);
#pragma unroll
        for(int rr=0;rr<4;rr++)
          hnew[(lq*4+rr)*272 + d] = (unsigned char)((packed >> (8*rr)) & 0xff);
      }
      __syncthreads();
      *(int*)hout = *(const int*)(hnew + w*272 + lane*4);
      hout  += 32768;
      xbase += 131072;
      xa0 = xn0; xa1 = xn1; xa2 = xn2; xa3 = xn3;
      p ^= 1;
    }
    {
      const unsigned char* hb = hbuf + p*4352;
      *(int*)(h_state + wg*4096 + w*256 + lane*4) = *(const int*)(hb + w*272 + lane*4);
#pragma unroll
      for(int i=0;i<4;i++) c_state[(wg*1024 + tid)*4 + i] = c[i];
    }

  } else if(bx < 16 + ng){
    // ================= GEMM branch (chunk k+1), dbuf B, NAMED buffers ======
    int q = tid >> 8;                 // quarter 0..3
    int t256 = tid & 255;
    int u = (bx - 16)*4 + q;          // unit in [0, 4*CT)
    int dir = u & 1;
    int v = u >> 1;                   // [0, 2*CT)
    int tl = v % CT;
    int rgh = v / CT;                 // [0,2): half of the 8 row-groups
    int tg = tb_gemm + tl;
    int tt = dir ? (511 - tg) : tg;
    short* a_shq = a_sh4 + q*4224;    // 16*264 shorts per quarter
    int w2 = t256 >> 6, lane = t256 & 63, lm = lane & 15, lq = lane >> 4;
    const short* wmat = wswz + ((long)dir << 18);
    const float* cbd  = cb + dir*1024;
    short* xgd = xg_wr + ((long)dir*CT + tl)*131072;

    for(int it=0; it<4; it++){
      int rg = rgh*4 + it;            // 16-row group in [0,8)
      {
        int row = t256 >> 4, seg = t256 & 15;
        int b = rg*16 + row;
        int idx = X[b*512 + tt];
        const float* erow = emb + (long)idx*256 + seg*16;
        float4 f0 = ((const float4*)erow)[0];
        float4 f1 = ((const float4*)erow)[1];
        float4 f2 = ((const float4*)erow)[2];
        float4 f3 = ((const float4*)erow)[3];
        v8s p0, p1;
        p0[0]=f2b(f0.x); p0[1]=f2b(f0.y); p0[2]=f2b(f0.z); p0[3]=f2b(f0.w);
        p0[4]=f2b(f1.x); p0[5]=f2b(f1.y); p0[6]=f2b(f1.z); p0[7]=f2b(f1.w);
        p1[0]=f2b(f2.x); p1[1]=f2b(f2.y); p1[2]=f2b(f2.z); p1[3]=f2b(f2.w);
        p1[4]=f2b(f3.x); p1[5]=f2b(f3.y); p1[6]=f2b(f3.z); p1[7]=f2b(f3.w);
        *(v8s*)(a_shq + row*264 + seg*16) = p0;
        *(v8s*)(a_shq + row*264 + seg*16 + 8) = p1;
      }
      __syncthreads();
      v8s A[8];
#pragma unroll
      for(int kk=0;kk<8;kk++)
        A[kk] = *(const v8s*)(a_shq + lm*264 + kk*32 + lq*8);

      v8s Bb0[8], Bb1[8];
      {
        const short* bp = wmat + (long)(w2*16)*4096 + lane*8;
#pragma unroll
        for(int kk=0;kk<8;kk++) Bb0[kk] = *(const v8s*)(bp + kk*512);
      }
#pragma unroll
      for(int ci=0; ci<16; ci+=2){
        {  // even: compute Bb0, prefetch Bb1
          int ct = w2*16 + ci;
          if(ci+1 < 16){
            const short* bp = wmat + (long)(ct+1)*4096 + lane*8;
#pragma unroll
            for(int kk=0;kk<8;kk++) Bb1[kk] = *(const v8s*)(bp + kk*512);
          }
          float bias = cbd[ct*16 + lm];
          v4f acc = (v4f){bias,bias,bias,bias};
#pragma unroll
          for(int kk=0;kk<8;kk++)
            acc = __builtin_amdgcn_mfma_f32_16x16x32_bf16(A[kk], Bb0[kk], acc, 0,0,0);
          long off = (long)rg*16384 + (long)(ct & 15)*1024 + (ct >> 4)*256 + lane*4;
          short4 s4;
          s4.x = f2b(acc[0]); s4.y = f2b(acc[1]);
          s4.z = f2b(acc[2]); s4.w = f2b(acc[3]);
          *(short4*)(xgd + off) = s4;
        }
        {  // odd: compute Bb1, prefetch Bb0
          int ct = w2*16 + ci + 1;
          if(ci+2 < 16){
            const short* bp = wmat + (long)(ct+1)*4096 + lane*8;
#pragma unroll
            for(int kk=0;kk<8;kk++) Bb0[kk] = *(const v8s*)(bp + kk*512);
          }
          float bias = cbd[ct*16 + lm];
          v4f acc = (v4f){bias,bias,bias,bias};
#pragma unroll
          for(int kk=0;kk<8;kk++)
            acc = __builtin_amdgcn_mfma_f32_16x16x32_bf16(A[kk], Bb1[kk], acc, 0,0,0);
          long off = (long)rg*16384 + (long)(ct & 15)*1024 + (ct >> 4)*256 + lane*4;
          short4 s4;
          s4.x = f2b(acc[0]); s4.y = f2b(acc[1]);
          s4.z = f2b(acc[2]); s4.w = f2b(acc[3]);
          *(short4*)(xgd + off) = s4;
        }
      }
      __syncthreads();   // before next it overwrites a_shq
    }

  } else {
    // ================= EMISS branch (chunk k-1): 16 wave-units =================
    int uv = (bx - 16 - ng)*16 + (tid >> 6);
    int lane = tid & 63;
    int per = CT << 7;                // CT*128 wave-units per dir
    int dir = (uv >= per) ? 1 : 0;
    int rest = uv - (dir ? per : 0);
    int tl = rest >> 7, b = rest & 127;
    int s = dir ? (511 - (tb_emiss + tl)) : (tb_emiss + tl);
    int v = *(const int*)(hg_rd + ((long)dir*CT + tl)*32768 + b*256 + lane*4);
    v2f lo = __builtin_amdgcn_cvt_pk_f32_fp8(v, 0);
    v2f hi = __builtin_amdgcn_cvt_pk_f32_fp8(v, 1);
    float x0 = lo[0], x1 = lo[1], x2 = hi[0], x3 = hi[1];
    const float* wbase = lin_w + dir*256 + lane*4;
    float part[9];
#pragma unroll
    for(int j=0;j<9;j++){
      float4 wf = *(const float4*)(wbase + j*512);
      part[j] = x0*wf.x + x1*wf.y + x2*wf.z + x3*wf.w;
    }
#pragma unroll
    for(int j=0;j<9;j++){
      float vv = part[j];
#pragma unroll
      for(int off=32; off>0; off>>=1) vv += __shfl_down(vv, off);
      if(lane == 0) em[((long)b*512 + s)*9 + j] += vv;
    }
  }
}

// ---------------------------------------------------------------------------
// CRF — LDS-staged (R18/R19)
// ---------------------------------------------------------------------------
__global__ __launch_bounds__(64) void crf_kernel(
                           const float* em, const int* y, const unsigned char* maskb,
                           const float* st, const float* en, const float* tr,
                           const float* lin_b, float* out)
{
  __shared__ __align__(16) float ems[4608];   // 18,432 B
  int b = blockIdx.x;
  int lane = threadIdx.x;

  {
    const float4* src = (const float4*)(em + (long)b*4608);
    float4* dst = (float4*)ems;
    for(int i = lane; i < 1152; i += 64) dst[i] = src[i];
  }

  bool isb = (maskb[1] != 0);
  int len = 0;
  for(int k=lane; k<512; k+=64){
    unsigned char mv = isb ? maskb[b*512 + k] : maskb[((long)(b*512 + k))*4];
    len += (mv != 0);
  }
#pragma unroll
  for(int off=32; off>0; off>>=1) len += __shfl_xor(len, off);

  __syncthreads();   // em staged

  const int* yb = y + b*512;
  float np = 0.f;
  for(int t=lane; t<512; t+=64){
    if(t >= 1 && t < len){
      int yp = yb[t-1], yt = yb[t];
      np += tr[yp*9 + yt] + ems[t*9 + yt] + lin_b[yt];
    }
  }
#pragma unroll
  for(int off=32; off>0; off>>=1) np += __shfl_xor(np, off);

  int j = lane;
  float alpha = -1e30f;
  float trc[9];
  float lb = (j < 9) ? lin_b[j] : 0.f;
  if(j < 9){
    alpha = st[j] + ems[j] + lb;
#pragma unroll
    for(int i=0;i<9;i++) trc[i] = tr[i*9 + j];
  }
  for(int t=1; t<len; t++){
    float av[9];
#pragma unroll
    for(int i=0;i<9;i++) av[i] = __shfl(alpha, i);
    if(j < 9){
      float m = av[0] + trc[0];
#pragma unroll
      for(int i=1;i<9;i++) m = fmaxf(m, av[i] + trc[i]);
      float ssum = 0.f;
#pragma unroll
      for(int i=0;i<9;i++) ssum += __expf(av[i] + trc[i] - m);
      alpha = m + __logf(ssum) + ems[t*9 + j] + lb;
    }
  }
  float aj = (j < 9) ? (alpha + en[j]) : -1e30f;
  float mm = aj;
#pragma unroll
  for(int off=32; off>0; off>>=1) mm = fmaxf(mm, __shfl_xor(mm, off));
  float ee = (j < 9) ? __expf(aj - mm) : 0.f;
#pragma unroll
  for(int off=32; off>0; off>>=1) ee += __shfl_xor(ee, off);
  float den = mm + __logf(ee);
  if(lane == 0){
    int y0 = yb[0];
    float num = np + st[y0] + ems[y0] + lin_b[y0] + en[yb[len-1]];
    atomicAdd(out, num - den);
  }
}

// ---------------------------------------------------------------------------
extern "C" void kernel_launch(void* const* d_in, const int* in_sizes, int n_in,
                              void* d_out, int out_size, void* d_ws, size_t ws_size,
                              hipStream_t stream)
{
  (void)in_sizes; (void)n_in; (void)out_size;
  const int*   X    = (const int*)d_in[0];
  const int*   y    = (const int*)d_in[1];
  const unsigned char* maskb = (const unsigned char*)d_in[2];
  const float* emb  = (const float*)d_in[3];
  const float* wihf = (const float*)d_in[4];
  const float* whhf = (const float*)d_in[5];
  const float* bihf = (const float*)d_in[6];
  const float* bhhf = (const float*)d_in[7];
  const float* wihb = (const float*)d_in[8];
  const float* whhb = (const float*)d_in[9];
  const float* bihb = (const float*)d_in[10];
  const float* bhhb = (const float*)d_in[11];
  const float* lin_w= (const float*)d_in[12];
  const float* lin_b= (const float*)d_in[13];
  const float* st   = (const float*)d_in[14];
  const float* en   = (const float*)d_in[15];
  const float* tr   = (const float*)d_in[16];

  // ring sizing: FIXED + 2*CT*(524288 + 65536) <= ws
  const long FIXED = 4595712L;
  long CT = 128;
  while (CT > 16 && FIXED + 2*CT*589824L > (long)ws_size) CT >>= 1;
  int NC = (int)(512 / CT);

  char* ws = (char*)d_ws;
  short*         wswz = (short*)(ws);                    // 1,048,576 B
  unsigned char* whh4 = (unsigned char*)(ws + 1572864L); //   262,144 B (MXFP4)
  int2*          whsc = (int2*)(ws + 1835008L);          //    65,536 B (scales)
  float*         cb   = (float*)(ws + 1900544L);         //     8,192 B
  float*         cst  = (float*)(ws + 1908736L);         //   262,144 B
  unsigned char* hst  = (unsigned char*)(ws + 2170880L); //    65,536 B
  float*         em   = (float*)(ws + 2236416L);         // 2,359,296 B
  short*         xg0  = (short*)(ws + FIXED);            // CT*524,288 B
  short*         xg1  = xg0 + CT*262144;                 // CT*524,288 B
  unsigned char* hg0  = (unsigned char*)(ws + FIXED + 2*CT*524288L); // CT*65,536 B
  unsigned char* hg1  = hg0 + CT*65536;                  // CT*65,536 B

  prep_kernel<<<512, 256, 0, stream>>>(wihf, whhf, wihb, whhb,
                                       bihf, bhhf, bihb, bhhb,
                                       wswz, whh4, whsc, cb, em, (float*)d_out);
  // chunk 0 gemm (exposed)
  xg_gemm<<<dim3(2*(int)CT, 2), 256, 0, stream>>>(X, emb, wswz, cb, xg0, 0, (int)CT);

  for(int k=0; k<NC; k++){
    short* xr = (k&1) ? xg1 : xg0;
    short* xw = (k&1) ? xg0 : xg1;            // slot (k+1)&1
    unsigned char* hw = (k&1) ? hg1 : hg0;
    unsigned char* hr = (k&1) ? hg0 : hg1;    // slot (k-1)&1
    int ng = (k+1 < NC) ? (int)CT : 0;        // gemm wgs (4 units, 4 its each)
    int ne = (k >= 1)   ? (int)(16*CT) : 0;   // emiss wgs (16 wave-units each)
    fused_step<<<16 + ng + ne, 1024, 0, stream>>>(
        X, emb, wswz, cb, xr, xw, whh4, whsc, hw, hr, cst, hst, lin_w, em,
        (k==0) ? 1 : 0, (int)CT, (k+1)*(int)CT, (k-1)*(int)CT, ng);
  }
  unsigned char* hlast = ((NC-1)&1) ? hg1 : hg0;
  emiss_partial<<<dim3(32*(int)CT, 2), 256, 0, stream>>>(hlast, lin_w, em, (NC-1)*(int)CT, (int)CT);
  crf_kernel<<<128, 64, 0, stream>>>(em, y, maskb, st, en, tr, lin_b, (float*)d_out);
}

// Round 11
// 904.046 us; speedup vs baseline: 2.2608x; 2.2608x over previous
//
#include <hip/hip_runtime.h>

// ---------------------------------------------------------------------------
// BiLSTM + CRF on MI355X — R21: 4x scan CUs via batch-split + shfl gate
// redistribution. R20 post-mortem: dbuf-B spills at the 64-VGPR wall every
// time -> abandoned. R19 ledger: scan 4x199us, trans-issue-bound at 4
// cells/thread. Batch rows are independent -> 64 scan wgs (2dir x 32 groups
// of 4 rows), M=16 MFMA with rows 0-3 live (A rows 4-15 zeroed in LDS),
// then __shfl-redistribute the 4 valid acc rows so EVERY lane computes 1
// cell (row=lq, d=16w+lm): per-wave trans issue /4, no cross-wg traffic.
// Shadow gemm/emiss branches and standalone kernels unchanged from R19.
// ---------------------------------------------------------------------------

typedef short v8s __attribute__((ext_vector_type(8)));
typedef float v4f __attribute__((ext_vector_type(4)));
typedef int   i4v __attribute__((ext_vector_type(4)));
typedef int   i8v __attribute__((ext_vector_type(8)));
typedef float v2f __attribute__((ext_vector_type(2)));

#define LOG2E  1.4426950408889634f
#define LOG2E2 2.8853900817779268f

__device__ __forceinline__ short f2b(float f){
  unsigned u = __float_as_uint(f);
  u = u + 0x7fffu + ((u >> 16) & 1u);          // RNE
  return (short)(u >> 16);
}
__device__ __forceinline__ float b2f(short s){
  return __uint_as_float(((unsigned)(unsigned short)s) << 16);
}
__device__ __forceinline__ float rcp_(float x){ return __builtin_amdgcn_rcpf(x); }
__device__ __forceinline__ float ex2(float x){ return __builtin_amdgcn_exp2f(x); }
__device__ __forceinline__ float med3(float x, float lo, float hi){
  return __builtin_amdgcn_fmed3f(x, lo, hi);
}
// e2m1 nearest: mags {0,.5,1,1.5,2,3,4,6}, code = sign<<3 | mag-index
__device__ __forceinline__ int fp4q(float v){
  int s = (v < 0.f) ? 8 : 0;
  float av = fabsf(v);
  int m;
  if(av < 0.25f) m=0; else if(av < 0.75f) m=1; else if(av < 1.25f) m=2;
  else if(av < 1.75f) m=3; else if(av < 2.5f) m=4; else if(av < 3.5f) m=5;
  else if(av < 5.f) m=6; else m=7;
  return s | m;
}

// ---------------------------------------------------------------------------
// prep: (unchanged — weights/biases gate-scaled for exp2)
// ---------------------------------------------------------------------------
__global__ void prep_kernel(const float* wihf, const float* whhf,
                            const float* wihb, const float* whhb,
                            const float* bihf, const float* bhhf,
                            const float* bihb, const float* bhhb,
                            short* wswz, unsigned char* whh4, int2* whsc,
                            float* cb, float* em, float* outp)
{
  int gid = blockIdx.x * 256 + threadIdx.x;      // 131072 threads
  if(gid < 65536){
    int mat = gid >> 15;                 // 0 = fwd, 1 = bwd
    int rem = gid & 32767;
    int ct = rem >> 9;
    int kk = (rem >> 6) & 7;
    int lane = rem & 63;
    const float* src = mat ? wihb : wihf;
    int g  = ct*16 + (lane & 15);
    float fac = ((g >> 8) == 2) ? LOG2E2 : LOG2E;
    int k0 = kk*32 + (lane >> 4)*8;
    v8s o;
#pragma unroll
    for(int j=0;j<8;j++) o[j] = f2b(src[g*256 + k0 + j] * fac);
    *(v8s*)(wswz + ((long)mat << 18) + ((long)((ct*8+kk)*64 + lane) << 3)) = o;
  } else if(gid < 73728){
    int j2 = gid - 65536;                // 8192
    int dir = j2 >> 12;
    int rem = j2 & 4095;
    int ct = rem >> 6;
    int lane = rem & 63;
    const float* src = dir ? whhb : whhf;
    int g = ct*16 + (lane & 15);
    float fac = ((g >> 8) == 2) ? LOG2E2 : LOG2E;
    int sc0 = 127, sc1 = 127;
#pragma unroll
    for(int half=0; half<2; half++){
      const float* s = src + g*256 + half*128 + (lane>>4)*32;
      float am = 0.f;
#pragma unroll
      for(int j=0;j<32;j++) am = fmaxf(am, fabsf(s[j]*fac));
      int e = 0;
      if(am > 0.f){
        e = (int)ceilf(log2f(am * (1.f/6.f)));
        e = e < -126 ? -126 : (e > 127 ? 127 : e);
      }
      float inv = exp2f((float)(-e)) * fac;
      i4v ov;
#pragma unroll
      for(int wi=0; wi<4; wi++){
        int word = 0;
#pragma unroll
        for(int bj=0; bj<4; bj++){
          int j0 = (wi*4 + bj)*2;        // low nibble = lower k
          int c0 = fp4q(s[j0]*inv), c1 = fp4q(s[j0+1]*inv);
          word |= (c0 | (c1<<4)) << (8*bj);
        }
        ov[wi] = word;
      }
      *(i4v*)(whh4 + ((long)((dir*64+ct)*2 + half) << 10) + lane*16) = ov;
      if(half == 0) sc0 = e + 127; else sc1 = e + 127;
    }
    whsc[(dir*64+ct)*64 + lane] = make_int2(sc0, sc1);
  } else if(gid >= 106496 && gid < 108544){
    int j3 = gid - 106496;
    int dir = j3 >> 10, gg = j3 & 1023;
    float fac = ((gg >> 8) == 2) ? LOG2E2 : LOG2E;
    cb[j3] = fac * (dir ? (bihb[gg] + bhhb[gg]) : (bihf[gg] + bhhf[gg]));
  }
  for(int i=gid; i<589824; i+=131072) em[i] = 0.f;
  if(gid == 0) *outp = 0.f;
}

// ---------------------------------------------------------------------------
// xg_gemm: standalone (chunk 0 only). Unchanged.
// ---------------------------------------------------------------------------
__global__ __launch_bounds__(256,2) void xg_gemm(const int* X, const float* emb,
     const short* wswz, const float* cb, short* xg, int t_base, int CT)
{
  int dir = blockIdx.x & 1;
  int tl  = blockIdx.x >> 1;
  int rh  = blockIdx.y;
  int tg  = t_base + tl;
  int tt  = dir ? (511 - tg) : tg;
  __shared__ short a_sh[64*264];
  int tid = threadIdx.x;
  {
    int row = tid >> 2, seg = tid & 3;
    int b = rh*64 + row;
    int idx = X[b*512 + tt];
    const float* erow = emb + (long)idx*256 + seg*64;
    short* dst = a_sh + row*264 + seg*64;
#pragma unroll
    for(int c=0;c<8;c++){
      float4 f0 = ((const float4*)erow)[2*c];
      float4 f1 = ((const float4*)erow)[2*c+1];
      v8s p;
      p[0]=f2b(f0.x); p[1]=f2b(f0.y); p[2]=f2b(f0.z); p[3]=f2b(f0.w);
      p[4]=f2b(f1.x); p[5]=f2b(f1.y); p[6]=f2b(f1.z); p[7]=f2b(f1.w);
      *(v8s*)(dst + c*8) = p;
    }
  }
  __syncthreads();
  int w = tid >> 6, lane = tid & 63, lm = lane & 15, lq = lane >> 4;
  v8s A[4][8];
#pragma unroll
  for(int mt=0;mt<4;mt++)
#pragma unroll
    for(int kk=0;kk<8;kk++)
      A[mt][kk] = *(const v8s*)(a_sh + (mt*16+lm)*264 + kk*32 + lq*8);

  const short* wmat = wswz + ((long)dir << 18);
  const float* cbd  = cb + dir*1024;
  short* xgd = xg + ((long)dir*CT + tl)*131072;

  v8s Bb[2][8];
  {
    const short* bp = wmat + (long)(w*16)*4096 + lane*8;
#pragma unroll
    for(int kk=0;kk<8;kk++) Bb[0][kk] = *(const v8s*)(bp + kk*512);
  }
#pragma unroll
  for(int ci=0;ci<16;ci++){
    int cur = ci & 1;
    int ct = w*16 + ci;
    if(ci < 15){
      const short* bp = wmat + (long)(ct+1)*4096 + lane*8;
#pragma unroll
      for(int kk=0;kk<8;kk++) Bb[cur^1][kk] = *(const v8s*)(bp + kk*512);
    }
    float bias = cbd[ct*16 + lm];
    v4f acc[4];
#pragma unroll
    for(int mt=0;mt<4;mt++) acc[mt] = (v4f){bias,bias,bias,bias};
#pragma unroll
    for(int kk=0;kk<8;kk++)
#pragma unroll
      for(int mt=0;mt<4;mt++)
        acc[mt] = __builtin_amdgcn_mfma_f32_16x16x32_bf16(A[mt][kk], Bb[cur][kk], acc[mt], 0,0,0);
#pragma unroll
    for(int mt=0;mt<4;mt++){
      int r = rh*4 + mt;
      long off = (long)r*16384 + (long)(ct & 15)*1024 + (ct >> 4)*256 + lane*4;
      short4 s4;
      s4.x = f2b(acc[mt][0]); s4.y = f2b(acc[mt][1]);
      s4.z = f2b(acc[mt][2]); s4.w = f2b(acc[mt][3]);
      *(short4*)(xgd + off) = s4;
    }
  }
}

// ---------------------------------------------------------------------------
// emiss_partial: standalone (last chunk only). Unchanged.
// ---------------------------------------------------------------------------
__global__ void emiss_partial(const unsigned char* hg8, const float* lin_w,
                              float* em, int t_base, int CT)
{
  int dir = blockIdx.y;
  int wv  = blockIdx.x*4 + (threadIdx.x >> 6);
  int lane = threadIdx.x & 63;
  int tl = wv >> 7, b = wv & 127;
  int s = dir ? (511 - (t_base + tl)) : (t_base + tl);
  int v = *(const int*)(hg8 + ((long)dir*CT + tl)*32768 + b*256 + lane*4);
  v2f lo = __builtin_amdgcn_cvt_pk_f32_fp8(v, 0);
  v2f hi = __builtin_amdgcn_cvt_pk_f32_fp8(v, 1);
  float x0 = lo[0], x1 = lo[1], x2 = hi[0], x3 = hi[1];
  const float* wbase = lin_w + dir*256 + lane*4;
  float part[9];
#pragma unroll
  for(int j=0;j<9;j++){
    float4 wf = *(const float4*)(wbase + j*512);
    part[j] = x0*wf.x + x1*wf.y + x2*wf.z + x3*wf.w;
  }
#pragma unroll
  for(int j=0;j<9;j++){
    float vv = part[j];
#pragma unroll
    for(int off=32; off>0; off>>=1) vv += __shfl_down(vv, off);
    if(lane == 0) em[((long)b*512 + s)*9 + j] += vv;
  }
}

// ---------------------------------------------------------------------------
// fused_step: one launch per chunk k.
//   bx < 64     : scan(chunk k) — 4 rows/wg, shfl gate redistribution,
//                 1 cell/thread
//   bx < 64+ng  : gemm(chunk k+1) — R19's proven single-buf branch
//   else        : emiss(chunk k-1)
// ---------------------------------------------------------------------------
__global__ __launch_bounds__(1024,1) void fused_step(
     const int* __restrict__ X, const float* __restrict__ emb,
     const short* __restrict__ wswz, const float* __restrict__ cb,
     const short* __restrict__ xg_rd, short* __restrict__ xg_wr,
     const unsigned char* __restrict__ whh4, const int2* __restrict__ whsc,
     unsigned char* __restrict__ hg_wr, const unsigned char* __restrict__ hg_rd,
     float* __restrict__ c_state, unsigned char* __restrict__ h_state,
     const float* __restrict__ lin_w, float* __restrict__ em,
     int first, int CT, int tb_gemm, int tb_emiss, int ng)
{
  __shared__ __align__(16) short a_sh4[4*16*264];   // 33,792 B (gemm); scan uses first 8704
  int bx = blockIdx.x;
  int tid = threadIdx.x;

  if(bx < 64){
    // ================= SCAN branch: 4 rows/wg =================
    unsigned char* hbuf = (unsigned char*)a_sh4;     // 2 x 4352 B, rows 4-15 stay 0
    int wg = bx;
    int dir = wg >> 5, rg = wg & 31;                 // 32 rowgroups of 4 rows
    int w = tid >> 6, lane = tid & 63, lm = lane & 15, lq = lane >> 4;

    i8v B8[4][2];
#pragma unroll
    for(int grp=0; grp<4; grp++)
#pragma unroll
      for(int half=0; half<2; half++){
        i4v b = *(const i4v*)(whh4 + ((long)((dir*64 + grp*16 + w)*2 + half) << 10) + lane*16);
        i8v t;
#pragma unroll
        for(int j=0;j<4;j++){ t[j] = b[j]; t[4+j] = 0; }
        B8[grp][half] = t;
      }
    int scp[2];
#pragma unroll
    for(int gp=0; gp<2; gp++){
      int2 s0 = whsc[(dir*64 + (2*gp+0)*16 + w)*64 + lane];
      int2 s1 = whsc[(dir*64 + (2*gp+1)*16 + w)*64 + lane];
      scp[gp] = (s0.x & 255) | ((s0.y & 255) << 8) | ((s1.x & 255) << 16) | ((s1.y & 255) << 24);
    }

    // zero both hbuf buffers (rows 4-15 must be 0 for the M=16 MFMA)
    for(int i=tid; i<8704; i+=1024) hbuf[i] = 0;
    float c = first ? 0.f : c_state[wg*1024 + tid];
    __syncthreads();
    if(!first && tid < 256){
      int row = tid >> 6, col = tid & 63;
      *(int*)(hbuf + row*272 + col*4) = *(const int*)(h_state + wg*1024 + row*256 + col*4);
    }
    __syncthreads();

    // xv: quadrant (rg&3) of 16-row group (rg>>2); broadcast to all lq
    const short* __restrict__ xbase =
        xg_rd + ((long)dir*CT)*131072 + (long)(rg >> 2)*16384 + w*1024 + ((rg & 3)*16 + lm)*4;
    int hrow = tid >> 6, hcol = tid & 63;            // for tid<256 store role
    unsigned char* __restrict__ houtb =
        hg_wr + (long)dir*CT*32768 + (rg*4 + hrow)*256 + hcol*4;

    short4 xa0 = *(const short4*)(xbase);
    short4 xa1 = *(const short4*)(xbase + 256);
    short4 xa2 = *(const short4*)(xbase + 512);
    short4 xa3 = *(const short4*)(xbase + 768);

    int p = 0;
    for(int tl=0; tl<CT; tl++){
      const short* __restrict__ xn = xbase + 131072;
      short4 xn0 = *(const short4*)(xn);
      short4 xn1 = *(const short4*)(xn + 256);
      short4 xn2 = *(const short4*)(xn + 512);
      short4 xn3 = *(const short4*)(xn + 768);

      const unsigned char* hb = hbuf + p*4352;
      union { i8v v8; i4v v4[2]; } a0, a1;
      a0.v4[0] = *(const i4v*)(hb + lm*272 + lq*32);
      a0.v4[1] = *(const i4v*)(hb + lm*272 + lq*32 + 16);
      a1.v4[0] = *(const i4v*)(hb + lm*272 + 128 + lq*32);
      a1.v4[1] = *(const i4v*)(hb + lm*272 + 128 + lq*32 + 16);

      v4f acc[4];
      acc[0] = (v4f){b2f(xa0.x), b2f(xa0.y), b2f(xa0.z), b2f(xa0.w)};
      acc[1] = (v4f){b2f(xa1.x), b2f(xa1.y), b2f(xa1.z), b2f(xa1.w)};
      acc[2] = (v4f){b2f(xa2.x), b2f(xa2.y), b2f(xa2.z), b2f(xa2.w)};
      acc[3] = (v4f){b2f(xa3.x), b2f(xa3.y), b2f(xa3.z), b2f(xa3.w)};

      acc[0] = __builtin_amdgcn_mfma_scale_f32_16x16x128_f8f6f4(a0.v8, B8[0][0], acc[0], 0, 4, 0, 127, 0, scp[0]);
      acc[0] = __builtin_amdgcn_mfma_scale_f32_16x16x128_f8f6f4(a1.v8, B8[0][1], acc[0], 0, 4, 0, 127, 1, scp[0]);
      acc[1] = __builtin_amdgcn_mfma_scale_f32_16x16x128_f8f6f4(a0.v8, B8[1][0], acc[1], 0, 4, 0, 127, 2, scp[0]);
      acc[1] = __builtin_amdgcn_mfma_scale_f32_16x16x128_f8f6f4(a1.v8, B8[1][1], acc[1], 0, 4, 0, 127, 3, scp[0]);
      acc[2] = __builtin_amdgcn_mfma_scale_f32_16x16x128_f8f6f4(a0.v8, B8[2][0], acc[2], 0, 4, 0, 127, 0, scp[1]);
      acc[2] = __builtin_amdgcn_mfma_scale_f32_16x16x128_f8f6f4(a1.v8, B8[2][1], acc[2], 0, 4, 0, 127, 1, scp[1]);
      acc[3] = __builtin_amdgcn_mfma_scale_f32_16x16x128_f8f6f4(a0.v8, B8[3][0], acc[3], 0, 4, 0, 127, 2, scp[1]);
      acc[3] = __builtin_amdgcn_mfma_scale_f32_16x16x128_f8f6f4(a1.v8, B8[3][1], acc[3], 0, 4, 0, 127, 3, scp[1]);

      // redistribute: gate for cell (row=lq, d=16w+lm) from lq=0 lane lm
      float g0, g1, g2, g3;
      {
        float s0 = __shfl(acc[0][0], lm), s1 = __shfl(acc[0][1], lm);
        float s2 = __shfl(acc[0][2], lm), s3 = __shfl(acc[0][3], lm);
        g0 = (lq < 2) ? (lq == 0 ? s0 : s1) : (lq == 2 ? s2 : s3);
      }
      {
        float s0 = __shfl(acc[1][0], lm), s1 = __shfl(acc[1][1], lm);
        float s2 = __shfl(acc[1][2], lm), s3 = __shfl(acc[1][3], lm);
        g1 = (lq < 2) ? (lq == 0 ? s0 : s1) : (lq == 2 ? s2 : s3);
      }
      {
        float s0 = __shfl(acc[2][0], lm), s1 = __shfl(acc[2][1], lm);
        float s2 = __shfl(acc[2][2], lm), s3 = __shfl(acc[2][3], lm);
        g2 = (lq < 2) ? (lq == 0 ? s0 : s1) : (lq == 2 ? s2 : s3);
      }
      {
        float s0 = __shfl(acc[3][0], lm), s1 = __shfl(acc[3][1], lm);
        float s2 = __shfl(acc[3][2], lm), s3 = __shfl(acc[3][3], lm);
        g3 = (lq < 2) ? (lq == 0 ? s0 : s1) : (lq == 2 ? s2 : s3);
      }

      unsigned char* hnew = hbuf + (p^1)*4352;
      {
        // 1 cell: row=lq, d=16w+lm
        float ig = g0;
        float fg = g1;
        float gg = med3(g2, -40.f, 40.f);
        float og = g3;
        float t  = ex2(gg);
        float a  = ex2(-ig);
        float b  = ex2(-fg);
        float u  = ex2(-og);
        float term = (t - 1.f) * rcp_((1.f + a)*(1.f + t));
        float cn = c*rcp_(1.f + b) + term;
        c = cn;
        float cc = med3(cn*LOG2E2, -40.f, 40.f);
        float d2 = ex2(cc);
        float hv = (d2 - 1.f)*rcp_((1.f + u)*(1.f + d2));
        int packed = __builtin_amdgcn_cvt_pk_fp8_f32(hv, hv, 0, 0);
        hnew[lq*272 + 16*w + lm] = (unsigned char)(packed & 0xff);
      }
      __syncthreads();
      if(tid < 256)
        *(int*)houtb = *(const int*)(hnew + hrow*272 + hcol*4);
      houtb += 32768;
      xbase += 131072;
      xa0 = xn0; xa1 = xn1; xa2 = xn2; xa3 = xn3;
      p ^= 1;
    }
    {
      const unsigned char* hb = hbuf + p*4352;
      if(tid < 256)
        *(int*)(h_state + wg*1024 + hrow*256 + hcol*4) = *(const int*)(hb + hrow*272 + hcol*4);
      c_state[wg*1024 + tid] = c;
    }

  } else if(bx < 64 + ng){
    // ================= GEMM branch (chunk k+1), single-buf B (R19) =========
    int q = tid >> 8;                 // quarter 0..3
    int t256 = tid & 255;
    int u = (bx - 64)*4 + q;          // unit in [0, 4*CT)
    int dir = u & 1;
    int v = u >> 1;                   // [0, 2*CT)
    int tl = v % CT;
    int rgh = v / CT;                 // [0,2): half of the 8 row-groups
    int tg = tb_gemm + tl;
    int tt = dir ? (511 - tg) : tg;
    short* a_shq = a_sh4 + q*4224;    // 16*264 shorts per quarter
    int w2 = t256 >> 6, lane = t256 & 63, lm = lane & 15, lq = lane >> 4;
    const short* wmat = wswz + ((long)dir << 18);
    const float* cbd  = cb + dir*1024;
    short* xgd = xg_wr + ((long)dir*CT + tl)*131072;

    for(int it=0; it<4; it++){
      int rg = rgh*4 + it;            // 16-row group in [0,8)
      {
        int row = t256 >> 4, seg = t256 & 15;
        int b = rg*16 + row;
        int idx = X[b*512 + tt];
        const float* erow = emb + (long)idx*256 + seg*16;
        float4 f0 = ((const float4*)erow)[0];
        float4 f1 = ((const float4*)erow)[1];
        float4 f2 = ((const float4*)erow)[2];
        float4 f3 = ((const float4*)erow)[3];
        v8s p0, p1;
        p0[0]=f2b(f0.x); p0[1]=f2b(f0.y); p0[2]=f2b(f0.z); p0[3]=f2b(f0.w);
        p0[4]=f2b(f1.x); p0[5]=f2b(f1.y); p0[6]=f2b(f1.z); p0[7]=f2b(f1.w);
        p1[0]=f2b(f2.x); p1[1]=f2b(f2.y); p1[2]=f2b(f2.z); p1[3]=f2b(f2.w);
        p1[4]=f2b(f3.x); p1[5]=f2b(f3.y); p1[6]=f2b(f3.z); p1[7]=f2b(f3.w);
        *(v8s*)(a_shq + row*264 + seg*16) = p0;
        *(v8s*)(a_shq + row*264 + seg*16 + 8) = p1;
      }
      __syncthreads();
      v8s A[8];
#pragma unroll
      for(int kk=0;kk<8;kk++)
        A[kk] = *(const v8s*)(a_shq + lm*264 + kk*32 + lq*8);

#pragma unroll 1
      for(int ci=0; ci<16; ci++){
        int ct = w2*16 + ci;
        const short* bp = wmat + (long)ct*4096 + lane*8;
        v8s Bb[8];
#pragma unroll
        for(int kk=0;kk<8;kk++) Bb[kk] = *(const v8s*)(bp + kk*512);
        float bias = cbd[ct*16 + lm];
        v4f acc = (v4f){bias,bias,bias,bias};
#pragma unroll
        for(int kk=0;kk<8;kk++)
          acc = __builtin_amdgcn_mfma_f32_16x16x32_bf16(A[kk], Bb[kk], acc, 0,0,0);
        long off = (long)rg*16384 + (long)(ct & 15)*1024 + (ct >> 4)*256 + lane*4;
        short4 s4;
        s4.x = f2b(acc[0]); s4.y = f2b(acc[1]);
        s4.z = f2b(acc[2]); s4.w = f2b(acc[3]);
        *(short4*)(xgd + off) = s4;
      }
      __syncthreads();   // before next it overwrites a_shq
    }

  } else {
    // ================= EMISS branch (chunk k-1): 16 wave-units =================
    int uv = (bx - 64 - ng)*16 + (tid >> 6);
    int lane = tid & 63;
    int per = CT << 7;                // CT*128 wave-units per dir
    int dir = (uv >= per) ? 1 : 0;
    int rest = uv - (dir ? per : 0);
    int tl = rest >> 7, b = rest & 127;
    int s = dir ? (511 - (tb_emiss + tl)) : (tb_emiss + tl);
    int v = *(const int*)(hg_rd + ((long)dir*CT + tl)*32768 + b*256 + lane*4);
    v2f lo = __builtin_amdgcn_cvt_pk_f32_fp8(v, 0);
    v2f hi = __builtin_amdgcn_cvt_pk_f32_fp8(v, 1);
    float x0 = lo[0], x1 = lo[1], x2 = hi[0], x3 = hi[1];
    const float* wbase = lin_w + dir*256 + lane*4;
    float part[9];
#pragma unroll
    for(int j=0;j<9;j++){
      float4 wf = *(const float4*)(wbase + j*512);
      part[j] = x0*wf.x + x1*wf.y + x2*wf.z + x3*wf.w;
    }
#pragma unroll
    for(int j=0;j<9;j++){
      float vv = part[j];
#pragma unroll
      for(int off=32; off>0; off>>=1) vv += __shfl_down(vv, off);
      if(lane == 0) em[((long)b*512 + s)*9 + j] += vv;
    }
  }
}

// ---------------------------------------------------------------------------
// CRF — LDS-staged (R18/R19)
// ---------------------------------------------------------------------------
__global__ __launch_bounds__(64) void crf_kernel(
                           const float* em, const int* y, const unsigned char* maskb,
                           const float* st, const float* en, const float* tr,
                           const float* lin_b, float* out)
{
  __shared__ __align__(16) float ems[4608];   // 18,432 B
  int b = blockIdx.x;
  int lane = threadIdx.x;

  {
    const float4* src = (const float4*)(em + (long)b*4608);
    float4* dst = (float4*)ems;
    for(int i = lane; i < 1152; i += 64) dst[i] = src[i];
  }

  bool isb = (maskb[1] != 0);
  int len = 0;
  for(int k=lane; k<512; k+=64){
    unsigned char mv = isb ? maskb[b*512 + k] : maskb[((long)(b*512 + k))*4];
    len += (mv != 0);
  }
#pragma unroll
  for(int off=32; off>0; off>>=1) len += __shfl_xor(len, off);

  __syncthreads();   // em staged

  const int* yb = y + b*512;
  float np = 0.f;
  for(int t=lane; t<512; t+=64){
    if(t >= 1 && t < len){
      int yp = yb[t-1], yt = yb[t];
      np += tr[yp*9 + yt] + ems[t*9 + yt] + lin_b[yt];
    }
  }
#pragma unroll
  for(int off=32; off>0; off>>=1) np += __shfl_xor(np, off);

  int j = lane;
  float alpha = -1e30f;
  float trc[9];
  float lb = (j < 9) ? lin_b[j] : 0.f;
  if(j < 9){
    alpha = st[j] + ems[j] + lb;
#pragma unroll
    for(int i=0;i<9;i++) trc[i] = tr[i*9 + j];
  }
  for(int t=1; t<len; t++){
    float av[9];
#pragma unroll
    for(int i=0;i<9;i++) av[i] = __shfl(alpha, i);
    if(j < 9){
      float m = av[0] + trc[0];
#pragma unroll
      for(int i=1;i<9;i++) m = fmaxf(m, av[i] + trc[i]);
      float ssum = 0.f;
#pragma unroll
      for(int i=0;i<9;i++) ssum += __expf(av[i] + trc[i] - m);
      alpha = m + __logf(ssum) + ems[t*9 + j] + lb;
    }
  }
  float aj = (j < 9) ? (alpha + en[j]) : -1e30f;
  float mm = aj;
#pragma unroll
  for(int off=32; off>0; off>>=1) mm = fmaxf(mm, __shfl_xor(mm, off));
  float ee = (j < 9) ? __expf(aj - mm) : 0.f;
#pragma unroll
  for(int off=32; off>0; off>>=1) ee += __shfl_xor(ee, off);
  float den = mm + __logf(ee);
  if(lane == 0){
    int y0 = yb[0];
    float num = np + st[y0] + ems[y0] + lin_b[y0] + en[yb[len-1]];
    atomicAdd(out, num - den);
  }
}

// ---------------------------------------------------------------------------
extern "C" void kernel_launch(void* const* d_in, const int* in_sizes, int n_in,
                              void* d_out, int out_size, void* d_ws, size_t ws_size,
                              hipStream_t stream)
{
  (void)in_sizes; (void)n_in; (void)out_size;
  const int*   X    = (const int*)d_in[0];
  const int*   y    = (const int*)d_in[1];
  const unsigned char* maskb = (const unsigned char*)d_in[2];
  const float* emb  = (const float*)d_in[3];
  const float* wihf = (const float*)d_in[4];
  const float* whhf = (const float*)d_in[5];
  const float* bihf = (const float*)d_in[6];
  const float* bhhf = (const float*)d_in[7];
  const float* wihb = (const float*)d_in[8];
  const float* whhb = (const float*)d_in[9];
  const float* bihb = (const float*)d_in[10];
  const float* bhhb = (const float*)d_in[11];
  const float* lin_w= (const float*)d_in[12];
  const float* lin_b= (const float*)d_in[13];
  const float* st   = (const float*)d_in[14];
  const float* en   = (const float*)d_in[15];
  const float* tr   = (const float*)d_in[16];

  // ring sizing: FIXED + 2*CT*(524288 + 65536) <= ws
  const long FIXED = 4595712L;
  long CT = 128;
  while (CT > 16 && FIXED + 2*CT*589824L > (long)ws_size) CT >>= 1;
  int NC = (int)(512 / CT);

  char* ws = (char*)d_ws;
  short*         wswz = (short*)(ws);                    // 1,048,576 B
  unsigned char* whh4 = (unsigned char*)(ws + 1572864L); //   262,144 B (MXFP4)
  int2*          whsc = (int2*)(ws + 1835008L);          //    65,536 B (scales)
  float*         cb   = (float*)(ws + 1900544L);         //     8,192 B
  float*         cst  = (float*)(ws + 1908736L);         //   262,144 B (64 wgs x 4 KB)
  unsigned char* hst  = (unsigned char*)(ws + 2170880L); //    65,536 B (64 wgs x 1 KB)
  float*         em   = (float*)(ws + 2236416L);         // 2,359,296 B
  short*         xg0  = (short*)(ws + FIXED);            // CT*524,288 B
  short*         xg1  = xg0 + CT*262144;                 // CT*524,288 B
  unsigned char* hg0  = (unsigned char*)(ws + FIXED + 2*CT*524288L); // CT*65,536 B
  unsigned char* hg1  = hg0 + CT*65536;                  // CT*65,536 B

  prep_kernel<<<512, 256, 0, stream>>>(wihf, whhf, wihb, whhb,
                                       bihf, bhhf, bihb, bhhb,
                                       wswz, whh4, whsc, cb, em, (float*)d_out);
  // chunk 0 gemm (exposed)
  xg_gemm<<<dim3(2*(int)CT, 2), 256, 0, stream>>>(X, emb, wswz, cb, xg0, 0, (int)CT);

  for(int k=0; k<NC; k++){
    short* xr = (k&1) ? xg1 : xg0;
    short* xw = (k&1) ? xg0 : xg1;            // slot (k+1)&1
    unsigned char* hw = (k&1) ? hg1 : hg0;
    unsigned char* hr = (k&1) ? hg0 : hg1;    // slot (k-1)&1
    int ng = (k+1 < NC) ? (int)CT : 0;        // gemm wgs (4 units, 4 its each)
    int ne = (k >= 1)   ? (int)(16*CT) : 0;   // emiss wgs (16 wave-units each)
    fused_step<<<64 + ng + ne, 1024, 0, stream>>>(
        X, emb, wswz, cb, xr, xw, whh4, whsc, hw, hr, cst, hst, lin_w, em,
        (k==0) ? 1 : 0, (int)CT, (k+1)*(int)CT, (k-1)*(int)CT, ng);
  }
  unsigned char* hlast = ((NC-1)&1) ? hg1 : hg0;
  emiss_partial<<<dim3(32*(int)CT, 2), 256, 0, stream>>>(hlast, lin_w, em, (NC-1)*(int)CT, (int)CT);
  crf_kernel<<<128, 64, 0, stream>>>(em, y, maskb, st, en, tr, lin_b, (float*)d_out);
}

// Round 12
// 816.186 us; speedup vs baseline: 2.5042x; 1.1076x over previous
//
#include <hip/hip_runtime.h>

// ---------------------------------------------------------------------------
// BiLSTM + CRF on MI355X — R22: replicated-A gates, no shfl redistribution.
// R21 (904us): 64-wg scan works, but step is chained on 16 ds_bpermute
// (shfl redistribute) + bank conflicts 2.5M. Fix: A-frag lanes read LDS row
// (lm&3) -> MFMA A rows = the wg's 4 batch rows replicated 4x -> C[m][n]
// holds batch row (m&3) => acc[g][rr] = gates[row rr][col lm] in EVERY lane.
// Redistribution = 3 compile-time v_cndmask per gate (rule-#20-safe).
// A-read becomes broadcast (conflict-free); xv C-in layout unchanged.
// Everything else identical to R21.
// ---------------------------------------------------------------------------

typedef short v8s __attribute__((ext_vector_type(8)));
typedef float v4f __attribute__((ext_vector_type(4)));
typedef int   i4v __attribute__((ext_vector_type(4)));
typedef int   i8v __attribute__((ext_vector_type(8)));
typedef float v2f __attribute__((ext_vector_type(2)));

#define LOG2E  1.4426950408889634f
#define LOG2E2 2.8853900817779268f

__device__ __forceinline__ short f2b(float f){
  unsigned u = __float_as_uint(f);
  u = u + 0x7fffu + ((u >> 16) & 1u);          // RNE
  return (short)(u >> 16);
}
__device__ __forceinline__ float b2f(short s){
  return __uint_as_float(((unsigned)(unsigned short)s) << 16);
}
__device__ __forceinline__ float rcp_(float x){ return __builtin_amdgcn_rcpf(x); }
__device__ __forceinline__ float ex2(float x){ return __builtin_amdgcn_exp2f(x); }
__device__ __forceinline__ float med3(float x, float lo, float hi){
  return __builtin_amdgcn_fmed3f(x, lo, hi);
}
__device__ __forceinline__ float selq(v4f v, int q){
  return q==0 ? v[0] : q==1 ? v[1] : q==2 ? v[2] : v[3];
}
// e2m1 nearest: mags {0,.5,1,1.5,2,3,4,6}, code = sign<<3 | mag-index
__device__ __forceinline__ int fp4q(float v){
  int s = (v < 0.f) ? 8 : 0;
  float av = fabsf(v);
  int m;
  if(av < 0.25f) m=0; else if(av < 0.75f) m=1; else if(av < 1.25f) m=2;
  else if(av < 1.75f) m=3; else if(av < 2.5f) m=4; else if(av < 3.5f) m=5;
  else if(av < 5.f) m=6; else m=7;
  return s | m;
}

// ---------------------------------------------------------------------------
// prep: (unchanged — weights/biases gate-scaled for exp2)
// ---------------------------------------------------------------------------
__global__ void prep_kernel(const float* wihf, const float* whhf,
                            const float* wihb, const float* whhb,
                            const float* bihf, const float* bhhf,
                            const float* bihb, const float* bhhb,
                            short* wswz, unsigned char* whh4, int2* whsc,
                            float* cb, float* em, float* outp)
{
  int gid = blockIdx.x * 256 + threadIdx.x;      // 131072 threads
  if(gid < 65536){
    int mat = gid >> 15;                 // 0 = fwd, 1 = bwd
    int rem = gid & 32767;
    int ct = rem >> 9;
    int kk = (rem >> 6) & 7;
    int lane = rem & 63;
    const float* src = mat ? wihb : wihf;
    int g  = ct*16 + (lane & 15);
    float fac = ((g >> 8) == 2) ? LOG2E2 : LOG2E;
    int k0 = kk*32 + (lane >> 4)*8;
    v8s o;
#pragma unroll
    for(int j=0;j<8;j++) o[j] = f2b(src[g*256 + k0 + j] * fac);
    *(v8s*)(wswz + ((long)mat << 18) + ((long)((ct*8+kk)*64 + lane) << 3)) = o;
  } else if(gid < 73728){
    int j2 = gid - 65536;                // 8192
    int dir = j2 >> 12;
    int rem = j2 & 4095;
    int ct = rem >> 6;
    int lane = rem & 63;
    const float* src = dir ? whhb : whhf;
    int g = ct*16 + (lane & 15);
    float fac = ((g >> 8) == 2) ? LOG2E2 : LOG2E;
    int sc0 = 127, sc1 = 127;
#pragma unroll
    for(int half=0; half<2; half++){
      const float* s = src + g*256 + half*128 + (lane>>4)*32;
      float am = 0.f;
#pragma unroll
      for(int j=0;j<32;j++) am = fmaxf(am, fabsf(s[j]*fac));
      int e = 0;
      if(am > 0.f){
        e = (int)ceilf(log2f(am * (1.f/6.f)));
        e = e < -126 ? -126 : (e > 127 ? 127 : e);
      }
      float inv = exp2f((float)(-e)) * fac;
      i4v ov;
#pragma unroll
      for(int wi=0; wi<4; wi++){
        int word = 0;
#pragma unroll
        for(int bj=0; bj<4; bj++){
          int j0 = (wi*4 + bj)*2;        // low nibble = lower k
          int c0 = fp4q(s[j0]*inv), c1 = fp4q(s[j0+1]*inv);
          word |= (c0 | (c1<<4)) << (8*bj);
        }
        ov[wi] = word;
      }
      *(i4v*)(whh4 + ((long)((dir*64+ct)*2 + half) << 10) + lane*16) = ov;
      if(half == 0) sc0 = e + 127; else sc1 = e + 127;
    }
    whsc[(dir*64+ct)*64 + lane] = make_int2(sc0, sc1);
  } else if(gid >= 106496 && gid < 108544){
    int j3 = gid - 106496;
    int dir = j3 >> 10, gg = j3 & 1023;
    float fac = ((gg >> 8) == 2) ? LOG2E2 : LOG2E;
    cb[j3] = fac * (dir ? (bihb[gg] + bhhb[gg]) : (bihf[gg] + bhhf[gg]));
  }
  for(int i=gid; i<589824; i+=131072) em[i] = 0.f;
  if(gid == 0) *outp = 0.f;
}

// ---------------------------------------------------------------------------
// xg_gemm: standalone (chunk 0 only). Unchanged.
// ---------------------------------------------------------------------------
__global__ __launch_bounds__(256,2) void xg_gemm(const int* X, const float* emb,
     const short* wswz, const float* cb, short* xg, int t_base, int CT)
{
  int dir = blockIdx.x & 1;
  int tl  = blockIdx.x >> 1;
  int rh  = blockIdx.y;
  int tg  = t_base + tl;
  int tt  = dir ? (511 - tg) : tg;
  __shared__ short a_sh[64*264];
  int tid = threadIdx.x;
  {
    int row = tid >> 2, seg = tid & 3;
    int b = rh*64 + row;
    int idx = X[b*512 + tt];
    const float* erow = emb + (long)idx*256 + seg*64;
    short* dst = a_sh + row*264 + seg*64;
#pragma unroll
    for(int c=0;c<8;c++){
      float4 f0 = ((const float4*)erow)[2*c];
      float4 f1 = ((const float4*)erow)[2*c+1];
      v8s p;
      p[0]=f2b(f0.x); p[1]=f2b(f0.y); p[2]=f2b(f0.z); p[3]=f2b(f0.w);
      p[4]=f2b(f1.x); p[5]=f2b(f1.y); p[6]=f2b(f1.z); p[7]=f2b(f1.w);
      *(v8s*)(dst + c*8) = p;
    }
  }
  __syncthreads();
  int w = tid >> 6, lane = tid & 63, lm = lane & 15, lq = lane >> 4;
  v8s A[4][8];
#pragma unroll
  for(int mt=0;mt<4;mt++)
#pragma unroll
    for(int kk=0;kk<8;kk++)
      A[mt][kk] = *(const v8s*)(a_sh + (mt*16+lm)*264 + kk*32 + lq*8);

  const short* wmat = wswz + ((long)dir << 18);
  const float* cbd  = cb + dir*1024;
  short* xgd = xg + ((long)dir*CT + tl)*131072;

  v8s Bb[2][8];
  {
    const short* bp = wmat + (long)(w*16)*4096 + lane*8;
#pragma unroll
    for(int kk=0;kk<8;kk++) Bb[0][kk] = *(const v8s*)(bp + kk*512);
  }
#pragma unroll
  for(int ci=0;ci<16;ci++){
    int cur = ci & 1;
    int ct = w*16 + ci;
    if(ci < 15){
      const short* bp = wmat + (long)(ct+1)*4096 + lane*8;
#pragma unroll
      for(int kk=0;kk<8;kk++) Bb[cur^1][kk] = *(const v8s*)(bp + kk*512);
    }
    float bias = cbd[ct*16 + lm];
    v4f acc[4];
#pragma unroll
    for(int mt=0;mt<4;mt++) acc[mt] = (v4f){bias,bias,bias,bias};
#pragma unroll
    for(int kk=0;kk<8;kk++)
#pragma unroll
      for(int mt=0;mt<4;mt++)
        acc[mt] = __builtin_amdgcn_mfma_f32_16x16x32_bf16(A[mt][kk], Bb[cur][kk], acc[mt], 0,0,0);
#pragma unroll
    for(int mt=0;mt<4;mt++){
      int r = rh*4 + mt;
      long off = (long)r*16384 + (long)(ct & 15)*1024 + (ct >> 4)*256 + lane*4;
      short4 s4;
      s4.x = f2b(acc[mt][0]); s4.y = f2b(acc[mt][1]);
      s4.z = f2b(acc[mt][2]); s4.w = f2b(acc[mt][3]);
      *(short4*)(xgd + off) = s4;
    }
  }
}

// ---------------------------------------------------------------------------
// emiss_partial: standalone (last chunk only). Unchanged.
// ---------------------------------------------------------------------------
__global__ void emiss_partial(const unsigned char* hg8, const float* lin_w,
                              float* em, int t_base, int CT)
{
  int dir = blockIdx.y;
  int wv  = blockIdx.x*4 + (threadIdx.x >> 6);
  int lane = threadIdx.x & 63;
  int tl = wv >> 7, b = wv & 127;
  int s = dir ? (511 - (t_base + tl)) : (t_base + tl);
  int v = *(const int*)(hg8 + ((long)dir*CT + tl)*32768 + b*256 + lane*4);
  v2f lo = __builtin_amdgcn_cvt_pk_f32_fp8(v, 0);
  v2f hi = __builtin_amdgcn_cvt_pk_f32_fp8(v, 1);
  float x0 = lo[0], x1 = lo[1], x2 = hi[0], x3 = hi[1];
  const float* wbase = lin_w + dir*256 + lane*4;
  float part[9];
#pragma unroll
  for(int j=0;j<9;j++){
    float4 wf = *(const float4*)(wbase + j*512);
    part[j] = x0*wf.x + x1*wf.y + x2*wf.z + x3*wf.w;
  }
#pragma unroll
  for(int j=0;j<9;j++){
    float vv = part[j];
#pragma unroll
    for(int off=32; off>0; off>>=1) vv += __shfl_down(vv, off);
    if(lane == 0) em[((long)b*512 + s)*9 + j] += vv;
  }
}

// ---------------------------------------------------------------------------
// fused_step: one launch per chunk k.
//   bx < 64     : scan(chunk k) — 4 rows/wg, replicated-A, 1 cell/thread
//   bx < 64+ng  : gemm(chunk k+1) — R19's proven single-buf branch
//   else        : emiss(chunk k-1)
// ---------------------------------------------------------------------------
__global__ __launch_bounds__(1024,1) void fused_step(
     const int* __restrict__ X, const float* __restrict__ emb,
     const short* __restrict__ wswz, const float* __restrict__ cb,
     const short* __restrict__ xg_rd, short* __restrict__ xg_wr,
     const unsigned char* __restrict__ whh4, const int2* __restrict__ whsc,
     unsigned char* __restrict__ hg_wr, const unsigned char* __restrict__ hg_rd,
     float* __restrict__ c_state, unsigned char* __restrict__ h_state,
     const float* __restrict__ lin_w, float* __restrict__ em,
     int first, int CT, int tb_gemm, int tb_emiss, int ng)
{
  __shared__ __align__(16) short a_sh4[4*16*264];   // 33,792 B (gemm); scan uses first 8704
  int bx = blockIdx.x;
  int tid = threadIdx.x;

  if(bx < 64){
    // ================= SCAN branch: 4 rows/wg, replicated-A =================
    unsigned char* hbuf = (unsigned char*)a_sh4;     // 2 x 4352 B (rows 0-3 live)
    int wg = bx;
    int dir = wg >> 5, rg = wg & 31;                 // 32 rowgroups of 4 rows
    int w = tid >> 6, lane = tid & 63, lm = lane & 15, lq = lane >> 4;
    int lr = lm & 3;                                 // replicated A row

    i8v B8[4][2];
#pragma unroll
    for(int grp=0; grp<4; grp++)
#pragma unroll
      for(int half=0; half<2; half++){
        i4v b = *(const i4v*)(whh4 + ((long)((dir*64 + grp*16 + w)*2 + half) << 10) + lane*16);
        i8v t;
#pragma unroll
        for(int j=0;j<4;j++){ t[j] = b[j]; t[4+j] = 0; }
        B8[grp][half] = t;
      }
    int scp[2];
#pragma unroll
    for(int gp=0; gp<2; gp++){
      int2 s0 = whsc[(dir*64 + (2*gp+0)*16 + w)*64 + lane];
      int2 s1 = whsc[(dir*64 + (2*gp+1)*16 + w)*64 + lane];
      scp[gp] = (s0.x & 255) | ((s0.y & 255) << 8) | ((s1.x & 255) << 16) | ((s1.y & 255) << 24);
    }

    // zero both hbuf buffers (only rows 0-3 are read, but cheap)
    for(int i=tid; i<8704; i+=1024) hbuf[i] = 0;
    float c = first ? 0.f : c_state[wg*1024 + tid];
    __syncthreads();
    if(!first && tid < 256){
      int row = tid >> 6, col = tid & 63;
      *(int*)(hbuf + row*272 + col*4) = *(const int*)(h_state + wg*1024 + row*256 + col*4);
    }
    __syncthreads();

    // xv: quadrant (rg&3) of 16-row group (rg>>2); lq-invariant
    const short* __restrict__ xbase =
        xg_rd + ((long)dir*CT)*131072 + (long)(rg >> 2)*16384 + w*1024 + ((rg & 3)*16 + lm)*4;
    int hrow = tid >> 6, hcol = tid & 63;            // tid<256 store role
    unsigned char* __restrict__ houtb =
        hg_wr + (long)dir*CT*32768 + (rg*4 + hrow)*256 + hcol*4;

    short4 xa0 = *(const short4*)(xbase);
    short4 xa1 = *(const short4*)(xbase + 256);
    short4 xa2 = *(const short4*)(xbase + 512);
    short4 xa3 = *(const short4*)(xbase + 768);

    int p = 0;
    for(int tl=0; tl<CT; tl++){
      const short* __restrict__ xn = xbase + 131072;
      short4 xn0 = *(const short4*)(xn);
      short4 xn1 = *(const short4*)(xn + 256);
      short4 xn2 = *(const short4*)(xn + 512);
      short4 xn3 = *(const short4*)(xn + 768);

      const unsigned char* hb = hbuf + p*4352;
      // replicated A: lane reads row (lm&3) -> broadcast, conflict-free
      union { i8v v8; i4v v4[2]; } a0, a1;
      a0.v4[0] = *(const i4v*)(hb + lr*272 + lq*32);
      a0.v4[1] = *(const i4v*)(hb + lr*272 + lq*32 + 16);
      a1.v4[0] = *(const i4v*)(hb + lr*272 + 128 + lq*32);
      a1.v4[1] = *(const i4v*)(hb + lr*272 + 128 + lq*32 + 16);

      v4f acc[4];
      acc[0] = (v4f){b2f(xa0.x), b2f(xa0.y), b2f(xa0.z), b2f(xa0.w)};
      acc[1] = (v4f){b2f(xa1.x), b2f(xa1.y), b2f(xa1.z), b2f(xa1.w)};
      acc[2] = (v4f){b2f(xa2.x), b2f(xa2.y), b2f(xa2.z), b2f(xa2.w)};
      acc[3] = (v4f){b2f(xa3.x), b2f(xa3.y), b2f(xa3.z), b2f(xa3.w)};

      acc[0] = __builtin_amdgcn_mfma_scale_f32_16x16x128_f8f6f4(a0.v8, B8[0][0], acc[0], 0, 4, 0, 127, 0, scp[0]);
      acc[0] = __builtin_amdgcn_mfma_scale_f32_16x16x128_f8f6f4(a1.v8, B8[0][1], acc[0], 0, 4, 0, 127, 1, scp[0]);
      acc[1] = __builtin_amdgcn_mfma_scale_f32_16x16x128_f8f6f4(a0.v8, B8[1][0], acc[1], 0, 4, 0, 127, 2, scp[0]);
      acc[1] = __builtin_amdgcn_mfma_scale_f32_16x16x128_f8f6f4(a1.v8, B8[1][1], acc[1], 0, 4, 0, 127, 3, scp[0]);
      acc[2] = __builtin_amdgcn_mfma_scale_f32_16x16x128_f8f6f4(a0.v8, B8[2][0], acc[2], 0, 4, 0, 127, 0, scp[1]);
      acc[2] = __builtin_amdgcn_mfma_scale_f32_16x16x128_f8f6f4(a1.v8, B8[2][1], acc[2], 0, 4, 0, 127, 1, scp[1]);
      acc[3] = __builtin_amdgcn_mfma_scale_f32_16x16x128_f8f6f4(a0.v8, B8[3][0], acc[3], 0, 4, 0, 127, 2, scp[1]);
      acc[3] = __builtin_amdgcn_mfma_scale_f32_16x16x128_f8f6f4(a1.v8, B8[3][1], acc[3], 0, 4, 0, 127, 3, scp[1]);

      // every lane holds rows 0-3 of its col: select row lq (compile-time idx)
      float g0 = selq(acc[0], lq);
      float g1 = selq(acc[1], lq);
      float g2 = selq(acc[2], lq);
      float g3 = selq(acc[3], lq);

      unsigned char* hnew = hbuf + (p^1)*4352;
      {
        // 1 cell: row=lq, d=16w+lm
        float ig = g0;
        float fg = g1;
        float gg = med3(g2, -40.f, 40.f);
        float og = g3;
        float t  = ex2(gg);
        float a  = ex2(-ig);
        float b  = ex2(-fg);
        float u  = ex2(-og);
        float term = (t - 1.f) * rcp_((1.f + a)*(1.f + t));
        float cn = c*rcp_(1.f + b) + term;
        c = cn;
        float cc = med3(cn*LOG2E2, -40.f, 40.f);
        float d2 = ex2(cc);
        float hv = (d2 - 1.f)*rcp_((1.f + u)*(1.f + d2));
        int packed = __builtin_amdgcn_cvt_pk_fp8_f32(hv, hv, 0, 0);
        hnew[lq*272 + 16*w + lm] = (unsigned char)(packed & 0xff);
      }
      __syncthreads();
      if(tid < 256)
        *(int*)houtb = *(const int*)(hnew + hrow*272 + hcol*4);
      houtb += 32768;
      xbase += 131072;
      xa0 = xn0; xa1 = xn1; xa2 = xn2; xa3 = xn3;
      p ^= 1;
    }
    {
      const unsigned char* hb = hbuf + p*4352;
      if(tid < 256)
        *(int*)(h_state + wg*1024 + hrow*256 + hcol*4) = *(const int*)(hb + hrow*272 + hcol*4);
      c_state[wg*1024 + tid] = c;
    }

  } else if(bx < 64 + ng){
    // ================= GEMM branch (chunk k+1), single-buf B (R19) =========
    int q = tid >> 8;                 // quarter 0..3
    int t256 = tid & 255;
    int u = (bx - 64)*4 + q;          // unit in [0, 4*CT)
    int dir = u & 1;
    int v = u >> 1;                   // [0, 2*CT)
    int tl = v % CT;
    int rgh = v / CT;                 // [0,2): half of the 8 row-groups
    int tg = tb_gemm + tl;
    int tt = dir ? (511 - tg) : tg;
    short* a_shq = a_sh4 + q*4224;    // 16*264 shorts per quarter
    int w2 = t256 >> 6, lane = t256 & 63, lm = lane & 15, lq = lane >> 4;
    const short* wmat = wswz + ((long)dir << 18);
    const float* cbd  = cb + dir*1024;
    short* xgd = xg_wr + ((long)dir*CT + tl)*131072;

    for(int it=0; it<4; it++){
      int rg = rgh*4 + it;            // 16-row group in [0,8)
      {
        int row = t256 >> 4, seg = t256 & 15;
        int b = rg*16 + row;
        int idx = X[b*512 + tt];
        const float* erow = emb + (long)idx*256 + seg*16;
        float4 f0 = ((const float4*)erow)[0];
        float4 f1 = ((const float4*)erow)[1];
        float4 f2 = ((const float4*)erow)[2];
        float4 f3 = ((const float4*)erow)[3];
        v8s p0, p1;
        p0[0]=f2b(f0.x); p0[1]=f2b(f0.y); p0[2]=f2b(f0.z); p0[3]=f2b(f0.w);
        p0[4]=f2b(f1.x); p0[5]=f2b(f1.y); p0[6]=f2b(f1.z); p0[7]=f2b(f1.w);
        p1[0]=f2b(f2.x); p1[1]=f2b(f2.y); p1[2]=f2b(f2.z); p1[3]=f2b(f2.w);
        p1[4]=f2b(f3.x); p1[5]=f2b(f3.y); p1[6]=f2b(f3.z); p1[7]=f2b(f3.w);
        *(v8s*)(a_shq + row*264 + seg*16) = p0;
        *(v8s*)(a_shq + row*264 + seg*16 + 8) = p1;
      }
      __syncthreads();
      v8s A[8];
#pragma unroll
      for(int kk=0;kk<8;kk++)
        A[kk] = *(const v8s*)(a_shq + lm*264 + kk*32 + lq*8);

#pragma unroll 1
      for(int ci=0; ci<16; ci++){
        int ct = w2*16 + ci;
        const short* bp = wmat + (long)ct*4096 + lane*8;
        v8s Bb[8];
#pragma unroll
        for(int kk=0;kk<8;kk++) Bb[kk] = *(const v8s*)(bp + kk*512);
        float bias = cbd[ct*16 + lm];
        v4f acc = (v4f){bias,bias,bias,bias};
#pragma unroll
        for(int kk=0;kk<8;kk++)
          acc = __builtin_amdgcn_mfma_f32_16x16x32_bf16(A[kk], Bb[kk], acc, 0,0,0);
        long off = (long)rg*16384 + (long)(ct & 15)*1024 + (ct >> 4)*256 + lane*4;
        short4 s4;
        s4.x = f2b(acc[0]); s4.y = f2b(acc[1]);
        s4.z = f2b(acc[2]); s4.w = f2b(acc[3]);
        *(short4*)(xgd + off) = s4;
      }
      __syncthreads();   // before next it overwrites a_shq
    }

  } else {
    // ================= EMISS branch (chunk k-1): 16 wave-units =================
    int uv = (bx - 64 - ng)*16 + (tid >> 6);
    int lane = tid & 63;
    int per = CT << 7;                // CT*128 wave-units per dir
    int dir = (uv >= per) ? 1 : 0;
    int rest = uv - (dir ? per : 0);
    int tl = rest >> 7, b = rest & 127;
    int s = dir ? (511 - (tb_emiss + tl)) : (tb_emiss + tl);
    int v = *(const int*)(hg_rd + ((long)dir*CT + tl)*32768 + b*256 + lane*4);
    v2f lo = __builtin_amdgcn_cvt_pk_f32_fp8(v, 0);
    v2f hi = __builtin_amdgcn_cvt_pk_f32_fp8(v, 1);
    float x0 = lo[0], x1 = lo[1], x2 = hi[0], x3 = hi[1];
    const float* wbase = lin_w + dir*256 + lane*4;
    float part[9];
#pragma unroll
    for(int j=0;j<9;j++){
      float4 wf = *(const float4*)(wbase + j*512);
      part[j] = x0*wf.x + x1*wf.y + x2*wf.z + x3*wf.w;
    }
#pragma unroll
    for(int j=0;j<9;j++){
      float vv = part[j];
#pragma unroll
      for(int off=32; off>0; off>>=1) vv += __shfl_down(vv, off);
      if(lane == 0) em[((long)b*512 + s)*9 + j] += vv;
    }
  }
}

// ---------------------------------------------------------------------------
// CRF — LDS-staged (R18/R19)
// ---------------------------------------------------------------------------
__global__ __launch_bounds__(64) void crf_kernel(
                           const float* em, const int* y, const unsigned char* maskb,
                           const float* st, const float* en, const float* tr,
                           const float* lin_b, float* out)
{
  __shared__ __align__(16) float ems[4608];   // 18,432 B
  int b = blockIdx.x;
  int lane = threadIdx.x;

  {
    const float4* src = (const float4*)(em + (long)b*4608);
    float4* dst = (float4*)ems;
    for(int i = lane; i < 1152; i += 64) dst[i] = src[i];
  }

  bool isb = (maskb[1] != 0);
  int len = 0;
  for(int k=lane; k<512; k+=64){
    unsigned char mv = isb ? maskb[b*512 + k] : maskb[((long)(b*512 + k))*4];
    len += (mv != 0);
  }
#pragma unroll
  for(int off=32; off>0; off>>=1) len += __shfl_xor(len, off);

  __syncthreads();   // em staged

  const int* yb = y + b*512;
  float np = 0.f;
  for(int t=lane; t<512; t+=64){
    if(t >= 1 && t < len){
      int yp = yb[t-1], yt = yb[t];
      np += tr[yp*9 + yt] + ems[t*9 + yt] + lin_b[yt];
    }
  }
#pragma unroll
  for(int off=32; off>0; off>>=1) np += __shfl_xor(np, off);

  int j = lane;
  float alpha = -1e30f;
  float trc[9];
  float lb = (j < 9) ? lin_b[j] : 0.f;
  if(j < 9){
    alpha = st[j] + ems[j] + lb;
#pragma unroll
    for(int i=0;i<9;i++) trc[i] = tr[i*9 + j];
  }
  for(int t=1; t<len; t++){
    float av[9];
#pragma unroll
    for(int i=0;i<9;i++) av[i] = __shfl(alpha, i);
    if(j < 9){
      float m = av[0] + trc[0];
#pragma unroll
      for(int i=1;i<9;i++) m = fmaxf(m, av[i] + trc[i]);
      float ssum = 0.f;
#pragma unroll
      for(int i=0;i<9;i++) ssum += __expf(av[i] + trc[i] - m);
      alpha = m + __logf(ssum) + ems[t*9 + j] + lb;
    }
  }
  float aj = (j < 9) ? (alpha + en[j]) : -1e30f;
  float mm = aj;
#pragma unroll
  for(int off=32; off>0; off>>=1) mm = fmaxf(mm, __shfl_xor(mm, off));
  float ee = (j < 9) ? __expf(aj - mm) : 0.f;
#pragma unroll
  for(int off=32; off>0; off>>=1) ee += __shfl_xor(ee, off);
  float den = mm + __logf(ee);
  if(lane == 0){
    int y0 = yb[0];
    float num = np + st[y0] + ems[y0] + lin_b[y0] + en[yb[len-1]];
    atomicAdd(out, num - den);
  }
}

// ---------------------------------------------------------------------------
extern "C" void kernel_launch(void* const* d_in, const int* in_sizes, int n_in,
                              void* d_out, int out_size, void* d_ws, size_t ws_size,
                              hipStream_t stream)
{
  (void)in_sizes; (void)n_in; (void)out_size;
  const int*   X    = (const int*)d_in[0];
  const int*   y    = (const int*)d_in[1];
  const unsigned char* maskb = (const unsigned char*)d_in[2];
  const float* emb  = (const float*)d_in[3];
  const float* wihf = (const float*)d_in[4];
  const float* whhf = (const float*)d_in[5];
  const float* bihf = (const float*)d_in[6];
  const float* bhhf = (const float*)d_in[7];
  const float* wihb = (const float*)d_in[8];
  const float* whhb = (const float*)d_in[9];
  const float* bihb = (const float*)d_in[10];
  const float* bhhb = (const float*)d_in[11];
  const float* lin_w= (const float*)d_in[12];
  const float* lin_b= (const float*)d_in[13];
  const float* st   = (const float*)d_in[14];
  const float* en   = (const float*)d_in[15];
  const float* tr   = (const float*)d_in[16];

  // ring sizing: FIXED + 2*CT*(524288 + 65536) <= ws
  const long FIXED = 4595712L;
  long CT = 128;
  while (CT > 16 && FIXED + 2*CT*589824L > (long)ws_size) CT >>= 1;
  int NC = (int)(512 / CT);

  char* ws = (char*)d_ws;
  short*         wswz = (short*)(ws);                    // 1,048,576 B
  unsigned char* whh4 = (unsigned char*)(ws + 1572864L); //   262,144 B (MXFP4)
  int2*          whsc = (int2*)(ws + 1835008L);          //    65,536 B (scales)
  float*         cb   = (float*)(ws + 1900544L);         //     8,192 B
  float*         cst  = (float*)(ws + 1908736L);         //   262,144 B (64 wgs x 4 KB)
  unsigned char* hst  = (unsigned char*)(ws + 2170880L); //    65,536 B (64 wgs x 1 KB)
  float*         em   = (float*)(ws + 2236416L);         // 2,359,296 B
  short*         xg0  = (short*)(ws + FIXED);            // CT*524,288 B
  short*         xg1  = xg0 + CT*262144;                 // CT*524,288 B
  unsigned char* hg0  = (unsigned char*)(ws + FIXED + 2*CT*524288L); // CT*65,536 B
  unsigned char* hg1  = hg0 + CT*65536;                  // CT*65,536 B

  prep_kernel<<<512, 256, 0, stream>>>(wihf, whhf, wihb, whhb,
                                       bihf, bhhf, bihb, bhhb,
                                       wswz, whh4, whsc, cb, em, (float*)d_out);
  // chunk 0 gemm (exposed)
  xg_gemm<<<dim3(2*(int)CT, 2), 256, 0, stream>>>(X, emb, wswz, cb, xg0, 0, (int)CT);

  for(int k=0; k<NC; k++){
    short* xr = (k&1) ? xg1 : xg0;
    short* xw = (k&1) ? xg0 : xg1;            // slot (k+1)&1
    unsigned char* hw = (k&1) ? hg1 : hg0;
    unsigned char* hr = (k&1) ? hg0 : hg1;    // slot (k-1)&1
    int ng = (k+1 < NC) ? (int)CT : 0;        // gemm wgs (4 units, 4 its each)
    int ne = (k >= 1)   ? (int)(16*CT) : 0;   // emiss wgs (16 wave-units each)
    fused_step<<<64 + ng + ne, 1024, 0, stream>>>(
        X, emb, wswz, cb, xr, xw, whh4, whsc, hw, hr, cst, hst, lin_w, em,
        (k==0) ? 1 : 0, (int)CT, (k+1)*(int)CT, (k-1)*(int)CT, ng);
  }
  unsigned char* hlast = ((NC-1)&1) ? hg1 : hg0;
  emiss_partial<<<dim3(32*(int)CT, 2), 256, 0, stream>>>(hlast, lin_w, em, (NC-1)*(int)CT, (int)CT);
  crf_kernel<<<128, 64, 0, stream>>>(em, y, maskb, st, en, tr, lin_b, (float*)d_out);
}